// Round 5
// baseline (185.808 us; speedup 1.0000x reference)
//
#include <hip/hip_runtime.h>
#include <stdint.h>

#define NBATCH 8192
#define HID    128
#define DXC    64
#define NN     66
#define NSTEP  20
#define MROWS  16
#define RSTR   136   // rT LDS stride in bf16 elems (272 B rows)
#define DSTR   280   // duL LDS stride in bf16 elems (560 B rows)

typedef __attribute__((ext_vector_type(8))) short short8;
typedef __attribute__((ext_vector_type(4))) float f32x4;

static __device__ __forceinline__ ushort f2bf(float f) {
  union { float f; uint32_t u; } v; v.f = f;
  uint32_t u = v.u;
  u += 0x7fffu + ((u >> 16) & 1u);
  return (ushort)(u >> 16);
}

// ---------------- Threefry2x32 (JAX exact) ----------------
__device__ __forceinline__ void tf2x32(uint32_t k1, uint32_t k2,
                                       uint32_t x0, uint32_t x1,
                                       uint32_t &o0, uint32_t &o1) {
  uint32_t k3 = k1 ^ k2 ^ 0x1BD11BDAu;
  x0 += k1; x1 += k2;
#define RND(r) do { x0 += x1; x1 = (x1 << (r)) | (x1 >> (32 - (r))); x1 ^= x0; } while (0)
  RND(13); RND(15); RND(26); RND(6);
  x0 += k2; x1 += k3 + 1u;
  RND(17); RND(29); RND(16); RND(24);
  x0 += k3; x1 += k1 + 2u;
  RND(13); RND(15); RND(26); RND(6);
  x0 += k1; x1 += k2 + 3u;
  RND(17); RND(29); RND(16); RND(24);
  x0 += k2; x1 += k3 + 4u;
  RND(13); RND(15); RND(26); RND(6);
  x0 += k3; x1 += k1 + 5u;
#undef RND
  o0 = x0; o1 = x1;
}

// ---------------- XLA ErfInv32 (Giles) ----------------
__device__ __forceinline__ float erfinv_f(float x) {
  float w = -log1pf(-x * x);
  float p1, p2;
  {
    float ww = w - 2.5f;
    float p = 2.81022636e-08f;
    p = fmaf(p, ww, 3.43273939e-07f);
    p = fmaf(p, ww, -3.5233877e-06f);
    p = fmaf(p, ww, -4.39150654e-06f);
    p = fmaf(p, ww, 0.00021858087f);
    p = fmaf(p, ww, -0.00125372503f);
    p = fmaf(p, ww, -0.00417768164f);
    p = fmaf(p, ww, 0.246640727f);
    p = fmaf(p, ww, 1.50140941f);
    p1 = p;
  }
  {
    float ww = sqrtf(w) - 3.0f;
    float p = -0.000200214257f;
    p = fmaf(p, ww, 0.000100950558f);
    p = fmaf(p, ww, 0.00134934322f);
    p = fmaf(p, ww, -0.00367342844f);
    p = fmaf(p, ww, 0.00573950773f);
    p = fmaf(p, ww, -0.0076224613f);
    p = fmaf(p, ww, 0.00943887047f);
    p = fmaf(p, ww, 1.00167406f);
    p = fmaf(p, ww, 2.83297682f);
    p2 = p;
  }
  float p = (w < 5.0f) ? p1 : p2;
  return p * x;
}

__device__ __forceinline__ float bits_to_normal(uint32_t bits) {
  float f = __uint_as_float((bits >> 9) | 0x3F800000u) - 1.0f;
  const float LO = -0.99999994f;
  float u = fmaxf(LO, fmaf(f, 2.0f, LO));
  return 1.41421356237f * erfinv_f(u);
}

// ---------------- fused kernel: 8-wave teams, all weights register-resident ----------------
__global__ __launch_bounds__(512, 4) void ebm_fused(
    const float* __restrict__ x, const float* __restrict__ t_in,
    const float* __restrict__ Bp,
    const float* __restrict__ W_in, const float* __restrict__ b_in,
    const float* __restrict__ WT1, const float* __restrict__ bT1,
    const float* __restrict__ WT2,
    const float* __restrict__ WY1, const float* __restrict__ bY1,
    const float* __restrict__ WY2,
    float* __restrict__ out) {

  __shared__ __align__(16) ushort rT[MROWS * RSTR];
  __shared__ __align__(16) ushort duL[MROWS * DSTR];
  __shared__ __align__(16) float xs[MROWS * DXC];
  __shared__ float nbuf[NSTEP * 2 * MROWS];   // precomputed noise, [s][2*m+comp]
  __shared__ float gpart[8][MROWS][2];
  __shared__ uint32_t skeys[NSTEP][2];
  __shared__ float cb[NN];
  __shared__ float dsc[2];

  const int tid  = threadIdx.x;
  const int lane = tid & 63;
  const int wv   = tid >> 6;          // wave 0..7, owns coltile wv
  const int r16  = lane & 15;
  const int q    = lane >> 4;
  const int row  = tid >> 5;          // phase-A row 0..15 (32 threads/row)
  const int c4   = (tid & 31) * 4;    // phase-A columns c4..c4+3
  const int brow0 = blockIdx.x * MROWS;

  // ---- stage x tile, step keys, sigmoid row sums ----
  if (tid < 256) ((float4*)xs)[tid] = ((const float4*)(x + (size_t)brow0 * DXC))[tid];
  if (tid < NSTEP) {
    uint32_t o0, o1;
    tf2x32(0u, 42u, 0u, (uint32_t)tid, o0, o1);
    skeys[tid][0] = o0; skeys[tid][1] = o1;
  }
  if (tid < NN) {
    float rs = 0.f;
    for (int j = 0; j < NN; ++j) {
      if (j == tid) continue;
      if (tid == NN - 1 && j < DXC) continue;
      float v = Bp[tid * NN + j];
      rs += 1.f / (1.f + expf(-v));
    }
    cb[tid] = 1.f + rs / 66.f;
  }
  __syncthreads();
  if (tid < 2) {
    int i = 64 + tid;
    float s = 0.f;
    for (int j = 0; j < NN; ++j) {
      if (j == i) continue;
      if (i == NN - 1 && j < DXC) continue;
      float v = Bp[i * NN + j];
      s += (1.f / (1.f + expf(-v))) * cb[j];
    }
    dsc[tid] = cb[i] + s / 66.f;
  }
  __syncthreads();
  const float d64 = dsc[0], d65 = dsc[1];

  // ---- precompute ALL noise for this block's 16 rows x 20 steps ----
  for (int f = tid; f < NSTEP * 2 * MROWS; f += 512) {
    int s = f >> 5, rr = f & 31;
    uint32_t idx = (uint32_t)(2 * (brow0 + (rr >> 1)) + (rr & 1));
    uint32_t o0, o1;
    tf2x32(skeys[s][0], skeys[s][1], 0u, idx, o0, o1);
    nbuf[f] = bits_to_normal(o0 ^ o1);
  }

  // ---- per-lane coltile constants (n0 = my output column) ----
  const int n0 = 16 * wv + r16;
  const float bT1a = bT1[n0], bY1a = bY1[n0];
  const ushort wT2a = f2bf(WT2[n0]), wY2a = f2bf(WY2[n0]);
  const float wtA = W_in[64 * HID + n0], wyA = W_in[65 * HID + n0];
  const float4 wtk4 = *(const float4*)(W_in + 64 * HID + c4);
  const float4 wyk4 = *(const float4*)(W_in + 65 * HID + c4);

  // ---- bake all 4 fragment sets into registers (64 VGPRs total) ----
  // fwd (B-frag for u = r@Wd):  fT[kt][j] = d64*WT1[kt*32+q*8+j][n0]
  // bwd (B-frag for v = du@Wd^T): hT[kt][j] = d64*WT1[n0][kt*32+q*8+j]
  short8 fT[4], fY[4], hT[4], hY[4];
#pragma unroll
  for (int kt = 0; kt < 4; ++kt) {
    const int kb = kt * 32 + q * 8;
    short8 a, b;
#pragma unroll
    for (int j = 0; j < 8; ++j) {
      a[j] = (short)f2bf(d64 * WT1[(kb + j) * HID + n0]);
      b[j] = (short)f2bf(d65 * WY1[(kb + j) * HID + n0]);
    }
    fT[kt] = a; fY[kt] = b;
    const float4* pT = (const float4*)(WT1 + (size_t)n0 * HID + kb);
    const float4* pY = (const float4*)(WY1 + (size_t)n0 * HID + kb);
    float4 t0 = pT[0], t1 = pT[1], y0 = pY[0], y1 = pY[1];
    short8 c, e;
    c[0] = (short)f2bf(d64 * t0.x); c[1] = (short)f2bf(d64 * t0.y);
    c[2] = (short)f2bf(d64 * t0.z); c[3] = (short)f2bf(d64 * t0.w);
    c[4] = (short)f2bf(d64 * t1.x); c[5] = (short)f2bf(d64 * t1.y);
    c[6] = (short)f2bf(d64 * t1.z); c[7] = (short)f2bf(d64 * t1.w);
    e[0] = (short)f2bf(d65 * y0.x); e[1] = (short)f2bf(d65 * y0.y);
    e[2] = (short)f2bf(d65 * y0.z); e[3] = (short)f2bf(d65 * y0.w);
    e[4] = (short)f2bf(d65 * y1.x); e[5] = (short)f2bf(d65 * y1.y);
    e[6] = (short)f2bf(d65 * y1.z); e[7] = (short)f2bf(d65 * y1.w);
    hT[kt] = c; hY[kt] = e;
  }

  // ---- static h0 part for my (row, c4..c4+3) ----
  float h0x_[4];
  {
    float4 b4 = *(const float4*)(b_in + c4);
    h0x_[0] = b4.x; h0x_[1] = b4.y; h0x_[2] = b4.z; h0x_[3] = b4.w;
    for (int cc = 0; cc < DXC; ++cc) {
      float4 w4 = *(const float4*)(W_in + cc * HID + c4);
      float xv = xs[row * DXC + cc];
      h0x_[0] = fmaf(xv, w4.x, h0x_[0]);
      h0x_[1] = fmaf(xv, w4.y, h0x_[1]);
      h0x_[2] = fmaf(xv, w4.z, h0x_[2]);
      h0x_[3] = fmaf(xv, w4.w, h0x_[3]);
    }
  }

  // ---- z state in registers (per thread, own row; updated redundantly) ----
  float zt_r = t_in[brow0 + row];
  float zy_r = 0.f;
  __syncthreads();   // nbuf visible to all

  for (int s = 0; s < NSTEP; ++s) {
    // ---- A: r = relu(h0x + t*wt + y*wy) -> bf16 rT (b64 packed writes) ----
    {
      uint32_t p0, p1;
      {
        float h0 = fmaf(zy_r, wyk4.x, fmaf(zt_r, wtk4.x, h0x_[0]));
        float h1 = fmaf(zy_r, wyk4.y, fmaf(zt_r, wtk4.y, h0x_[1]));
        float h2 = fmaf(zy_r, wyk4.z, fmaf(zt_r, wtk4.z, h0x_[2]));
        float h3 = fmaf(zy_r, wyk4.w, fmaf(zt_r, wtk4.w, h0x_[3]));
        p0 = (uint32_t)f2bf(fmaxf(h0, 0.f)) | ((uint32_t)f2bf(fmaxf(h1, 0.f)) << 16);
        p1 = (uint32_t)f2bf(fmaxf(h2, 0.f)) | ((uint32_t)f2bf(fmaxf(h3, 0.f)) << 16);
      }
      uint2 st; st.x = p0; st.y = p1;
      *(uint2*)&rT[row * RSTR + c4] = st;
    }
    __syncthreads();

    // ---- F: forward u = d*(r@W) + b -> du masks into duL ----
    {
      short8 ar[4];
#pragma unroll
      for (int kt = 0; kt < 4; ++kt)
        ar[kt] = *reinterpret_cast<const short8*>(&rT[r16 * RSTR + kt * 32 + q * 8]);

      f32x4 aT = {0.f, 0.f, 0.f, 0.f}, aY = aT;
#pragma unroll
      for (int kt = 0; kt < 4; ++kt) {
        aT = __builtin_amdgcn_mfma_f32_16x16x32_bf16(ar[kt], fT[kt], aT, 0, 0, 0);
        aY = __builtin_amdgcn_mfma_f32_16x16x32_bf16(ar[kt], fY[kt], aY, 0, 0, 0);
      }
#pragma unroll
      for (int reg = 0; reg < 4; ++reg) {
        int rr = q * 4 + reg;
        duL[rr * DSTR + n0]       = (aT[reg] + bT1a > 0.f) ? wT2a : (ushort)0;
        duL[rr * DSTR + 128 + n0] = (aY[reg] + bY1a > 0.f) ? wY2a : (ushort)0;
      }
    }
    __syncthreads();

    // ---- B: backward v = du_T@(d64*WT1^T) + du_Y@(d65*WY1^T); mask; dots ----
    {
      short8 d8[4];
#pragma unroll
      for (int kt = 0; kt < 4; ++kt)
        d8[kt] = *reinterpret_cast<const short8*>(&duL[r16 * DSTR + kt * 32 + q * 8]);
      f32x4 g = {0.f, 0.f, 0.f, 0.f};
#pragma unroll
      for (int kt = 0; kt < 4; ++kt)
        g = __builtin_amdgcn_mfma_f32_16x16x32_bf16(d8[kt], hT[kt], g, 0, 0, 0);
#pragma unroll
      for (int kt = 0; kt < 4; ++kt)
        d8[kt] = *reinterpret_cast<const short8*>(&duL[r16 * DSTR + 128 + kt * 32 + q * 8]);
#pragma unroll
      for (int kt = 0; kt < 4; ++kt)
        g = __builtin_amdgcn_mfma_f32_16x16x32_bf16(d8[kt], hY[kt], g, 0, 0, 0);

      float pt[4], py[4];
#pragma unroll
      for (int reg = 0; reg < 4; ++reg) {
        int rr = q * 4 + reg;
        short rv = (short)rT[rr * RSTR + n0];
        float v = (rv > 0) ? g[reg] : 0.f;
        pt[reg] = v * wtA;
        py[reg] = v * wyA;
      }
#pragma unroll
      for (int reg = 0; reg < 4; ++reg) {
#pragma unroll
        for (int off = 1; off < 16; off <<= 1) {
          pt[reg] += __shfl_xor(pt[reg], off);
          py[reg] += __shfl_xor(py[reg], off);
        }
      }
      if (r16 == 0) {
#pragma unroll
        for (int reg = 0; reg < 4; ++reg) {
          gpart[wv][q * 4 + reg][0] = pt[reg];
          gpart[wv][q * 4 + reg][1] = py[reg];
        }
      }
    }
    __syncthreads();

    // ---- z update (every thread, own row; noise precomputed) ----
    {
      float gt = 0.f, gy = 0.f;
#pragma unroll
      for (int w = 0; w < 8; ++w) {
        gt += gpart[w][row][0];
        gy += gpart[w][row][1];
      }
      float nt = nbuf[s * 32 + 2 * row];
      float ny = nbuf[s * 32 + 2 * row + 1];
      zt_r = (zt_r - 0.005f * gt) + 0.1f * nt;
      zy_r = (zy_r - 0.005f * gy) + 0.1f * ny;
    }
  }

  if ((tid & 31) == 0) out[brow0 + row] = zy_r;
}

extern "C" void kernel_launch(void* const* d_in, const int* in_sizes, int n_in,
                              void* d_out, int out_size, void* d_ws, size_t ws_size,
                              hipStream_t stream) {
  const float* x    = (const float*)d_in[0];
  const float* t_in = (const float*)d_in[1];
  const float* Bp   = (const float*)d_in[2];
  const float* W_in = (const float*)d_in[3];
  const float* b_in = (const float*)d_in[4];
  const float* WT1  = (const float*)d_in[5];
  const float* bT1  = (const float*)d_in[6];
  const float* WT2  = (const float*)d_in[7];
  const float* WY1  = (const float*)d_in[9];
  const float* bY1  = (const float*)d_in[10];
  const float* WY2  = (const float*)d_in[11];
  float* out = (float*)d_out;

  ebm_fused<<<NBATCH / MROWS, 512, 0, stream>>>(
      x, t_in, Bp, W_in, b_in, WT1, bT1, WT2, WY1, bY1, WY2, out);
}